// Round 1
// baseline (337.811 us; speedup 1.0000x reference)
//
#include <hip/hip_runtime.h>

// DGCN layer: out = ((A_norm @ (h * outdeg^-.5)) * indeg^-1.5) @ W + bias
// A_norm edges weighted by 0.5^distance, aggregated by mean over dst mailbox.
// Strategy: build CSR-by-dst per call (int atomics only), gather-side
// aggregation (no float atomics), then fp32 LDS-tiled GEMM.

constexpr int D = 128;

__global__ void k_degrees(const int* __restrict__ src, const int* __restrict__ dst,
                          int* __restrict__ outd, int* __restrict__ ind, int E) {
    int e = blockIdx.x * blockDim.x + threadIdx.x;
    if (e < E) {
        atomicAdd(&outd[src[e]], 1);
        atomicAdd(&ind[dst[e]], 1);
    }
}

__global__ void k_scales(const int* __restrict__ outd, const int* __restrict__ ind,
                         float* __restrict__ oscale, float* __restrict__ iscale, int N) {
    int i = blockIdx.x * blockDim.x + threadIdx.x;
    if (i < N) {
        float od = (float)outd[i];
        float id = (float)ind[i];
        oscale[i] = rsqrtf(od);            // outdeg^-0.5
        iscale[i] = rsqrtf(id) / id;       // indeg^-1.5 (mean + final norm folded)
    }
}

// Single-block exclusive scan of in-degrees -> CSR offsets. Shuffle-based
// (wave64 scan, 16 wave sums, wave0 scans those) to keep barrier count low.
__global__ __launch_bounds__(1024) void k_scan(const int* __restrict__ ind,
                                               int* __restrict__ offs, int N) {
    __shared__ int wsum[16];
    __shared__ int sbase;
    int tid = threadIdx.x;
    int lane = tid & 63, w = tid >> 6;
    if (tid == 0) sbase = 0;
    __syncthreads();
    for (int start = 0; start < N; start += 1024) {
        int i = start + tid;
        int v = (i < N) ? ind[i] : 0;
        int x = v;
        #pragma unroll
        for (int off = 1; off < 64; off <<= 1) {
            int t = __shfl_up(x, off, 64);
            if (lane >= off) x += t;
        }
        if (lane == 63) wsum[w] = x;
        __syncthreads();
        if (w == 0) {
            int s = (lane < 16) ? wsum[lane] : 0;
            #pragma unroll
            for (int off = 1; off < 16; off <<= 1) {
                int t = __shfl_up(s, off, 64);
                if (lane >= off) s += t;
            }
            if (lane < 16) wsum[lane] = s;   // inclusive wave sums
        }
        __syncthreads();
        int wbase = (w > 0) ? wsum[w - 1] : 0;
        int base = sbase;
        if (i < N) offs[i] = base + wbase + x - v;   // exclusive
        int total = wsum[15];
        __syncthreads();
        if (tid == 0) sbase = base + total;
        __syncthreads();
    }
    if (threadIdx.x == 0) offs[N] = sbase;
}

__global__ void k_scatter(const int* __restrict__ src, const int* __restrict__ dst,
                          const int* __restrict__ dist, const float* __restrict__ oscale,
                          const int* __restrict__ offs, int* __restrict__ cursor,
                          int* __restrict__ esrc, float* __restrict__ ecoef, int E) {
    int e = blockIdx.x * blockDim.x + threadIdx.x;
    if (e < E) {
        int d = dst[e];
        int p = offs[d] + atomicAdd(&cursor[d], 1);
        int s = src[e];
        esrc[p] = s;
        // 0.5^dist exact via exponent manipulation
        ecoef[p] = ldexpf(oscale[s], -dist[e]);
    }
}

// One 32-lane group per dst node; each lane owns one float4 (128 floats/row).
__global__ void k_aggregate(const float* __restrict__ h, const int* __restrict__ esrc,
                            const float* __restrict__ ecoef, const int* __restrict__ offs,
                            const float* __restrict__ iscale, float* __restrict__ agg, int N) {
    int g = blockIdx.x * 8 + (threadIdx.x >> 5);   // node id
    int lane = threadIdx.x & 31;
    if (g >= N) return;
    int b = offs[g], e = offs[g + 1];
    const float4* h4 = (const float4*)h;
    float4 acc = make_float4(0.f, 0.f, 0.f, 0.f);
    for (int i = b; i < e; i++) {
        int s = esrc[i];
        float c = ecoef[i];
        float4 hv = h4[(size_t)s * 32 + lane];
        acc.x += c * hv.x; acc.y += c * hv.y; acc.z += c * hv.z; acc.w += c * hv.w;
    }
    float sc = iscale[g];
    acc.x *= sc; acc.y *= sc; acc.z *= sc; acc.w *= sc;
    ((float4*)agg)[(size_t)g * 32 + lane] = acc;
}

// out[N,128] = A[N,128] @ W[128,128] + bias. Block: 64 rows x 128 cols,
// 256 threads, each computes 4x8. K chunked by 32. A chunk staged transposed
// with stride 68 -> 16B-aligned b128 reads, 2-way bank conflicts only (free).
__global__ __launch_bounds__(256) void k_gemm(const float* __restrict__ A,
                                              const float* __restrict__ W,
                                              const float* __restrict__ bias,
                                              float* __restrict__ out, int N) {
    __shared__ float Ws[32 * 128];
    __shared__ float As[32 * 68];
    int tid = threadIdx.x;
    int tx = tid & 15, ty = tid >> 4;
    int row0 = blockIdx.x * 64;
    float acc[4][8];
    #pragma unroll
    for (int j = 0; j < 4; j++)
        #pragma unroll
        for (int l = 0; l < 8; l++) acc[j][l] = 0.f;

    for (int kc = 0; kc < 128; kc += 32) {
        #pragma unroll
        for (int i = 0; i < 16; i++) {          // 32x128 W chunk
            int idx = tid + i * 256;
            int k = idx >> 7, c = idx & 127;
            Ws[idx] = W[(kc + k) * 128 + c];
        }
        #pragma unroll
        for (int i = 0; i < 8; i++) {           // 64x32 A chunk, transposed
            int idx = tid + i * 256;
            int r = idx >> 5, k = idx & 31;
            int row = row0 + r;
            As[k * 68 + r] = (row < N) ? A[(size_t)row * D + kc + k] : 0.f;
        }
        __syncthreads();
        #pragma unroll
        for (int k = 0; k < 32; k++) {
            float4 a  = *(const float4*)&As[k * 68 + ty * 4];
            float4 w0 = *(const float4*)&Ws[k * 128 + tx * 4];
            float4 w1 = *(const float4*)&Ws[k * 128 + 64 + tx * 4];
            float av[4] = {a.x, a.y, a.z, a.w};
            float wv[8] = {w0.x, w0.y, w0.z, w0.w, w1.x, w1.y, w1.z, w1.w};
            #pragma unroll
            for (int j = 0; j < 4; j++)
                #pragma unroll
                for (int l = 0; l < 8; l++)
                    acc[j][l] += av[j] * wv[l];
        }
        __syncthreads();
    }
    float4 b0 = *(const float4*)&bias[tx * 4];
    float4 b1 = *(const float4*)&bias[64 + tx * 4];
    #pragma unroll
    for (int j = 0; j < 4; j++) {
        int row = row0 + ty * 4 + j;
        if (row < N) {
            float4 o0 = make_float4(acc[j][0] + b0.x, acc[j][1] + b0.y,
                                    acc[j][2] + b0.z, acc[j][3] + b0.w);
            float4 o1 = make_float4(acc[j][4] + b1.x, acc[j][5] + b1.y,
                                    acc[j][6] + b1.z, acc[j][7] + b1.w);
            *(float4*)&out[(size_t)row * D + tx * 4] = o0;
            *(float4*)&out[(size_t)row * D + 64 + tx * 4] = o1;
        }
    }
}

extern "C" void kernel_launch(void* const* d_in, const int* in_sizes, int n_in,
                              void* d_out, int out_size, void* d_ws, size_t ws_size,
                              hipStream_t stream) {
    const float* h    = (const float*)d_in[0];
    const int*   src  = (const int*)d_in[1];
    const int*   dst  = (const int*)d_in[2];
    const int*   dist = (const int*)d_in[3];
    const float* W    = (const float*)d_in[4];
    const float* bias = (const float*)d_in[5];
    float* out = (float*)d_out;
    const int N = in_sizes[0] / D;
    const int E = in_sizes[1];

    char* ws = (char*)d_ws;
    size_t p = 0;
    auto alloc = [&](size_t bytes) -> char* {
        char* r = ws + p;
        p = (p + bytes + 511) & ~(size_t)511;
        return r;
    };
    int*   outd   = (int*)alloc((size_t)N * 4);
    int*   ind    = (int*)alloc((size_t)N * 4);
    int*   cursor = (int*)alloc((size_t)N * 4);
    size_t zero_bytes = p;                    // outd + ind + cursor
    int*   offs   = (int*)alloc((size_t)(N + 1) * 4);
    float* oscale = (float*)alloc((size_t)N * 4);
    float* iscale = (float*)alloc((size_t)N * 4);
    int*   esrc   = (int*)alloc((size_t)E * 4);
    float* ecoef  = (float*)alloc((size_t)E * 4);
    float* agg    = (float*)alloc((size_t)N * D * 4);

    hipMemsetAsync(d_ws, 0, zero_bytes, stream);
    k_degrees<<<(E + 255) / 256, 256, 0, stream>>>(src, dst, outd, ind, E);
    k_scales<<<(N + 255) / 256, 256, 0, stream>>>(outd, ind, oscale, iscale, N);
    k_scan<<<1, 1024, 0, stream>>>(ind, offs, N);
    k_scatter<<<(E + 255) / 256, 256, 0, stream>>>(src, dst, dist, oscale, offs,
                                                   cursor, esrc, ecoef, E);
    k_aggregate<<<(N + 7) / 8, 256, 0, stream>>>(h, esrc, ecoef, offs, iscale, agg, N);
    k_gemm<<<(N + 63) / 64, 256, 0, stream>>>(agg, W, bias, out, N);
}

// Round 2
// 279.390 us; speedup vs baseline: 1.2091x; 1.2091x over previous
//
#include <hip/hip_runtime.h>

// DGCN layer: out = ((A_norm @ (h * outdeg^-.5)) * indeg^-1.5) @ W + bias
// R2: (a) parallel 3-phase scan (was single-block serial, ~100us on 1 CU),
//     (b) bf16-compressed gather: h cast to bf16 once, aggregate reads 256B
//         rows, accumulates fp32, writes agg as bf16; GEMM unpacks in LDS.

constexpr int D = 128;

__device__ __forceinline__ float bf16_to_f(unsigned int u16) {
    union { unsigned int u; float f; } c; c.u = u16 << 16; return c.f;
}
__device__ __forceinline__ unsigned int f_to_bf16(float f) {
    union { float f; unsigned int u; } c; c.f = f;
    unsigned int u = c.u;
    u += 0x7fffu + ((u >> 16) & 1u);   // RNE
    return u >> 16;
}

// ---- h (fp32) -> hs (bf16) ----
__global__ void k_cast(const float4* __restrict__ h4, ushort4* __restrict__ hs4, int n4) {
    int i = blockIdx.x * blockDim.x + threadIdx.x;
    if (i < n4) {
        float4 v = h4[i];
        ushort4 o;
        o.x = (unsigned short)f_to_bf16(v.x);
        o.y = (unsigned short)f_to_bf16(v.y);
        o.z = (unsigned short)f_to_bf16(v.z);
        o.w = (unsigned short)f_to_bf16(v.w);
        hs4[i] = o;
    }
}

__global__ void k_degrees(const int* __restrict__ src, const int* __restrict__ dst,
                          int* __restrict__ outd, int* __restrict__ ind, int E) {
    int e = blockIdx.x * blockDim.x + threadIdx.x;
    if (e < E) {
        atomicAdd(&outd[src[e]], 1);
        atomicAdd(&ind[dst[e]], 1);
    }
}

// ---- scan phase 1: per-block (2048 elems) sums ----
__global__ __launch_bounds__(256) void k_blocksum(const int* __restrict__ ind,
                                                  int* __restrict__ bsum, int N) {
    int tid = threadIdx.x;
    int base = blockIdx.x * 2048;
    int s = 0;
    #pragma unroll
    for (int j = 0; j < 8; j++) {
        int i = base + tid + j * 256;
        if (i < N) s += ind[i];
    }
    #pragma unroll
    for (int off = 32; off; off >>= 1) s += __shfl_down(s, off, 64);
    __shared__ int ws[4];
    if ((tid & 63) == 0) ws[tid >> 6] = s;
    __syncthreads();
    if (tid == 0) bsum[blockIdx.x] = ws[0] + ws[1] + ws[2] + ws[3];
}

// ---- scan phase 2: one wave scans the block sums (nb ~ 25) ----
__global__ void k_scansums(const int* __restrict__ bsum, int* __restrict__ bbase,
                           int* __restrict__ offs, int N, int nb) {
    int lane = threadIdx.x;   // 64 threads
    int carry = 0;
    for (int s0 = 0; s0 < nb; s0 += 64) {
        int i = s0 + lane;
        int v = (i < nb) ? bsum[i] : 0;
        int x = v;
        #pragma unroll
        for (int off = 1; off < 64; off <<= 1) {
            int t = __shfl_up(x, off, 64);
            if (lane >= off) x += t;
        }
        if (i < nb) bbase[i] = carry + x - v;
        carry += __shfl(x, 63, 64);
    }
    if (lane == 0) offs[N] = carry;
}

// ---- scan phase 3: per-block exclusive scan + fused scale computation ----
__global__ __launch_bounds__(256) void k_scanblock(const int* __restrict__ ind,
        const int* __restrict__ outd, const int* __restrict__ bbase,
        int* __restrict__ offs, float* __restrict__ oscale,
        float* __restrict__ iscale, int N) {
    int tid = threadIdx.x;
    int lane = tid & 63, w = tid >> 6;
    int i0 = blockIdx.x * 2048 + tid * 8;
    int v[8];
    int s = 0;
    #pragma unroll
    for (int j = 0; j < 8; j++) {
        v[j] = (i0 + j < N) ? ind[i0 + j] : 0;
        s += v[j];
    }
    int x = s;
    #pragma unroll
    for (int off = 1; off < 64; off <<= 1) {
        int t = __shfl_up(x, off, 64);
        if (lane >= off) x += t;
    }
    __shared__ int ws[4];
    if (lane == 63) ws[w] = x;
    __syncthreads();
    int wbase = 0;
    #pragma unroll
    for (int k = 0; k < 4; k++) if (k < w) wbase += ws[k];
    int run = bbase[blockIdx.x] + wbase + (x - s);
    #pragma unroll
    for (int j = 0; j < 8; j++) {
        int i = i0 + j;
        if (i < N) {
            offs[i] = run;
            float id = (float)v[j];
            iscale[i] = rsqrtf(id) / id;          // indeg^-1.5
            float od = (float)outd[i];
            oscale[i] = rsqrtf(od);               // outdeg^-0.5
        }
        run += v[j];
    }
}

__global__ void k_scatter(const int* __restrict__ src, const int* __restrict__ dst,
                          const int* __restrict__ dist, const float* __restrict__ oscale,
                          const int* __restrict__ offs, int* __restrict__ cursor,
                          int* __restrict__ esrc, float* __restrict__ ecoef, int E) {
    int e = blockIdx.x * blockDim.x + threadIdx.x;
    if (e < E) {
        int d = dst[e];
        int p = offs[d] + atomicAdd(&cursor[d], 1);
        int s = src[e];
        esrc[p] = s;
        ecoef[p] = ldexpf(oscale[s], -dist[e]);   // 0.5^dist exact
    }
}

// ---- gather-side aggregation, bf16 rows (256B), fp32 accumulate ----
// 16 lanes per dst node, each lane owns 8 bf16 (one uint4 = 16B).
__global__ __launch_bounds__(256) void k_aggregate(const uint4* __restrict__ hs4,
        const int* __restrict__ esrc, const float* __restrict__ ecoef,
        const int* __restrict__ offs, const float* __restrict__ iscale,
        uint4* __restrict__ aggb, int N) {
    int g = (blockIdx.x * blockDim.x + threadIdx.x) >> 4;
    int lane = threadIdx.x & 15;
    if (g >= N) return;
    int b = offs[g], e = offs[g + 1];
    float acc[8] = {0.f, 0.f, 0.f, 0.f, 0.f, 0.f, 0.f, 0.f};
    for (int i = b; i < e; i++) {
        int s = esrc[i];
        float c = ecoef[i];
        uint4 hv = hs4[(size_t)s * 16 + lane];
        acc[0] += c * bf16_to_f(hv.x & 0xffffu);
        acc[1] += c * bf16_to_f(hv.x >> 16);
        acc[2] += c * bf16_to_f(hv.y & 0xffffu);
        acc[3] += c * bf16_to_f(hv.y >> 16);
        acc[4] += c * bf16_to_f(hv.z & 0xffffu);
        acc[5] += c * bf16_to_f(hv.z >> 16);
        acc[6] += c * bf16_to_f(hv.w & 0xffffu);
        acc[7] += c * bf16_to_f(hv.w >> 16);
    }
    float sc = iscale[g];
    uint4 o;
    o.x = f_to_bf16(acc[0] * sc) | (f_to_bf16(acc[1] * sc) << 16);
    o.y = f_to_bf16(acc[2] * sc) | (f_to_bf16(acc[3] * sc) << 16);
    o.z = f_to_bf16(acc[4] * sc) | (f_to_bf16(acc[5] * sc) << 16);
    o.w = f_to_bf16(acc[6] * sc) | (f_to_bf16(acc[7] * sc) << 16);
    aggb[(size_t)g * 16 + lane] = o;
}

// out[N,128] = A(bf16)[N,128] @ W[128,128] + bias. fp32 math; A unpacked to
// fp32 in LDS. 64 rows x 128 cols per block, 256 threads, 4x8 each.
__global__ __launch_bounds__(256) void k_gemm(const unsigned short* __restrict__ A,
                                              const float* __restrict__ W,
                                              const float* __restrict__ bias,
                                              float* __restrict__ out, int N) {
    __shared__ float Ws[32 * 128];
    __shared__ float As[32 * 68];
    int tid = threadIdx.x;
    int tx = tid & 15, ty = tid >> 4;
    int row0 = blockIdx.x * 64;
    float acc[4][8];
    #pragma unroll
    for (int j = 0; j < 4; j++)
        #pragma unroll
        for (int l = 0; l < 8; l++) acc[j][l] = 0.f;

    for (int kc = 0; kc < 128; kc += 32) {
        #pragma unroll
        for (int i = 0; i < 16; i++) {          // 32x128 W chunk
            int idx = tid + i * 256;
            int k = idx >> 7, c = idx & 127;
            Ws[idx] = W[(kc + k) * 128 + c];
        }
        #pragma unroll
        for (int i = 0; i < 8; i++) {           // 64x32 A chunk, transposed
            int idx = tid + i * 256;
            int r = idx >> 5, k = idx & 31;
            int row = row0 + r;
            As[k * 68 + r] = (row < N) ? bf16_to_f(A[(size_t)row * D + kc + k]) : 0.f;
        }
        __syncthreads();
        #pragma unroll
        for (int k = 0; k < 32; k++) {
            float4 a  = *(const float4*)&As[k * 68 + ty * 4];
            float4 w0 = *(const float4*)&Ws[k * 128 + tx * 4];
            float4 w1 = *(const float4*)&Ws[k * 128 + 64 + tx * 4];
            float av[4] = {a.x, a.y, a.z, a.w};
            float wv[8] = {w0.x, w0.y, w0.z, w0.w, w1.x, w1.y, w1.z, w1.w};
            #pragma unroll
            for (int j = 0; j < 4; j++)
                #pragma unroll
                for (int l = 0; l < 8; l++)
                    acc[j][l] += av[j] * wv[l];
        }
        __syncthreads();
    }
    float4 b0 = *(const float4*)&bias[tx * 4];
    float4 b1 = *(const float4*)&bias[64 + tx * 4];
    #pragma unroll
    for (int j = 0; j < 4; j++) {
        int row = row0 + ty * 4 + j;
        if (row < N) {
            float4 o0 = make_float4(acc[j][0] + b0.x, acc[j][1] + b0.y,
                                    acc[j][2] + b0.z, acc[j][3] + b0.w);
            float4 o1 = make_float4(acc[j][4] + b1.x, acc[j][5] + b1.y,
                                    acc[j][6] + b1.z, acc[j][7] + b1.w);
            *(float4*)&out[(size_t)row * D + tx * 4] = o0;
            *(float4*)&out[(size_t)row * D + 64 + tx * 4] = o1;
        }
    }
}

extern "C" void kernel_launch(void* const* d_in, const int* in_sizes, int n_in,
                              void* d_out, int out_size, void* d_ws, size_t ws_size,
                              hipStream_t stream) {
    const float* h    = (const float*)d_in[0];
    const int*   src  = (const int*)d_in[1];
    const int*   dst  = (const int*)d_in[2];
    const int*   dist = (const int*)d_in[3];
    const float* W    = (const float*)d_in[4];
    const float* bias = (const float*)d_in[5];
    float* out = (float*)d_out;
    const int N = in_sizes[0] / D;
    const int E = in_sizes[1];
    const int NB = (N + 2047) / 2048;

    char* ws = (char*)d_ws;
    size_t p = 0;
    auto alloc = [&](size_t bytes) -> char* {
        char* r = ws + p;
        p = (p + bytes + 511) & ~(size_t)511;
        return r;
    };
    int*   outd   = (int*)alloc((size_t)N * 4);
    int*   ind    = (int*)alloc((size_t)N * 4);
    int*   cursor = (int*)alloc((size_t)N * 4);
    size_t zero_bytes = p;                    // outd + ind + cursor
    int*   offs   = (int*)alloc((size_t)(N + 1) * 4);
    float* oscale = (float*)alloc((size_t)N * 4);
    float* iscale = (float*)alloc((size_t)N * 4);
    int*   bsum   = (int*)alloc((size_t)NB * 4);
    int*   bbase  = (int*)alloc((size_t)NB * 4);
    int*   esrc   = (int*)alloc((size_t)E * 4);
    float* ecoef  = (float*)alloc((size_t)E * 4);
    unsigned short* hs   = (unsigned short*)alloc((size_t)N * D * 2);
    unsigned short* aggb = (unsigned short*)alloc((size_t)N * D * 2);

    hipMemsetAsync(d_ws, 0, zero_bytes, stream);
    int n4 = N * D / 4;
    k_cast<<<(n4 + 255) / 256, 256, 0, stream>>>((const float4*)h, (ushort4*)hs, n4);
    k_degrees<<<(E + 255) / 256, 256, 0, stream>>>(src, dst, outd, ind, E);
    k_blocksum<<<NB, 256, 0, stream>>>(ind, bsum, N);
    k_scansums<<<1, 64, 0, stream>>>(bsum, bbase, offs, N, NB);
    k_scanblock<<<NB, 256, 0, stream>>>(ind, outd, bbase, offs, oscale, iscale, N);
    k_scatter<<<(E + 255) / 256, 256, 0, stream>>>(src, dst, dist, oscale, offs,
                                                   cursor, esrc, ecoef, E);
    k_aggregate<<<(N * 16 + 255) / 256, 256, 0, stream>>>((const uint4*)hs, esrc, ecoef,
                                                          offs, iscale, (uint4*)aggb, N);
    k_gemm<<<(N + 63) / 64, 256, 0, stream>>>(aggb, W, bias, out, N);
}